// Round 9
// baseline (151.060 us; speedup 1.0000x reference)
//
#include <hip/hip_runtime.h>
#include <hip/hip_bf16.h>

#define S_LEN 2048
#define D_MODEL 1024
#define NHEAD 16
#define HDIM 64
#define BATCH 2
#define M_TOT (BATCH * S_LEN)   // 4096
#define KVB 64

typedef __attribute__((ext_vector_type(4))) float f32x4;
typedef __attribute__((ext_vector_type(4))) short s16x4;
typedef __attribute__((ext_vector_type(8))) short s16x8;

#define AS1 __attribute__((address_space(1)))
#define AS3 __attribute__((address_space(3)))

#define SC2 0.18033688011112042f  // (1/8) * log2(e)

__device__ inline short f2bf(float f) {
  unsigned u = __float_as_uint(f);
  return (short)((u + 0x7fffu + ((u >> 16) & 1u)) >> 16);
}

// HW packed f32->bf16 (RNE). No builtin on gfx950 -> inline asm (T12 recipe).
__device__ __forceinline__ unsigned cvtpk(float lo, float hi) {
  unsigned r;
  asm("v_cvt_pk_bf16_f32 %0, %1, %2" : "=v"(r) : "v"(lo), "v"(hi));
  return r;
}
__device__ __forceinline__ s16x4 pk4(float a, float b, float c, float d) {
  union { unsigned u[2]; s16x4 s; } x;
  x.u[0] = cvtpk(a, b);
  x.u[1] = cvtpk(c, d);
  return x.s;
}

__device__ __forceinline__ void gl_lds16(const short* g, short* l) {
  __builtin_amdgcn_global_load_lds((const AS1 void*)g, (AS3 void*)l, 16, 0, 0);
}

// ---------------------------------------------------------------------------
// X fp32 -> bf16 cast. grid 2048, block 256, 8 elems/thread.
// ---------------------------------------------------------------------------
__global__ __launch_bounds__(256) void xcast_k(const float* __restrict__ X,
                                               short* __restrict__ Xb) {
  const size_t i = ((size_t)blockIdx.x * 256 + threadIdx.x) * 8;
  float4 a = *(const float4*)&X[i];
  float4 b = *(const float4*)&X[i + 4];
  s16x8 p;
  p[0] = f2bf(a.x); p[1] = f2bf(a.y); p[2] = f2bf(a.z); p[3] = f2bf(a.w);
  p[4] = f2bf(b.x); p[5] = f2bf(b.y); p[6] = f2bf(b.z); p[7] = f2bf(b.w);
  *(s16x8*)&Xb[i] = p;
}

// ---------------------------------------------------------------------------
// Weight transpose + cast, all 4 weights into contiguous Wcat[z][n][k].
// Wq (z==0) pre-scaled by (1/8)*log2(e). grid (32,32,4), block (32,8)
// ---------------------------------------------------------------------------
__global__ __launch_bounds__(256) void wtrans_k(const float* __restrict__ W0,
                                                const float* __restrict__ W1,
                                                const float* __restrict__ W2,
                                                const float* __restrict__ W3,
                                                short* __restrict__ Wcat) {
  const int z = blockIdx.z;
  const float* W = z == 0 ? W0 : z == 1 ? W1 : z == 2 ? W2 : W3;
  short* Wt = Wcat + (size_t)z * D_MODEL * D_MODEL;
  const float scl = (z == 0) ? SC2 : 1.f;
  __shared__ float tile[32][33];
  const int tx = threadIdx.x, ty = threadIdx.y;
  const int n0 = blockIdx.x * 32, k0 = blockIdx.y * 32;
#pragma unroll
  for (int j = 0; j < 4; ++j)
    tile[ty + j * 8][tx] = W[(size_t)(k0 + ty + j * 8) * D_MODEL + n0 + tx];
  __syncthreads();
#pragma unroll
  for (int j = 0; j < 4; ++j)
    Wt[(size_t)(n0 + ty + j * 8) * D_MODEL + k0 + tx] =
        f2bf(tile[tx][ty + j * 8] * scl);
}

// ---------------------------------------------------------------------------
// Fused QKV projection: tile 128x192, BK=64, grid 512, 4 waves.
// Round 9: ONLY A is LDS-staged (gl_lds16 + XOR slot-swizzle, 32 KB dbuf).
// B (weights) streams DIRECT global->VGPR per fragment (L2-hot: 4 blocks/XCD
// share each panel; the 2 wm-waves read identical bytes -> L1 hits), double-
// buffered in registers, issued one iter ahead so the barrier's vmcnt drain
// (needed for A anyway) covers them for free. LDS traffic/block-iter:
// 120 KB -> 48 KB (the identified bottleneck).
// ---------------------------------------------------------------------------
__global__ __launch_bounds__(256, 2) void gemm_qkv_k(
    const short* __restrict__ Xb, const short* __restrict__ Wcat,
    const float* __restrict__ bq, const float* __restrict__ bk,
    const float* __restrict__ bv, short* __restrict__ Qb,
    short* __restrict__ Kb, short* __restrict__ Vtb) {
  __shared__ short As[2 * 128 * 64];   // 32 KB
  const int orig = blockIdx.x;                 // 512 = 64 per XCD
  const int wg = (orig & 7) * 64 + (orig >> 3);
  const int m0 = (wg >> 4) * 128;              // n-fastest within XCD chunk
  const int n0 = (wg & 15) * 192;

  const int tid = threadIdx.x;
  const int lane = tid & 63, w = tid >> 6;
  const int wm = w >> 1, wn = w & 1;
  const int lr = lane & 15, lg = lane >> 4;
  const int lr8 = lane >> 3;
  const int sl = lane & 7;
  const int scol = ((sl ^ lr8) << 3);

  f32x4 acc[4][6] = {};

  auto stageA = [&](int buf, int k0) {
#pragma unroll
    for (int j = 0; j < 4; ++j) {
      const int rb = j * 4 + w;
      const int row = rb * 8 + lr8;
      gl_lds16(&Xb[(size_t)(m0 + row) * D_MODEL + k0 + scol],
               &As[buf * 8192 + rb * 512]);
    }
  };

  s16x8 bfr[2][2][6];  // [buf][ks][frag]
  auto loadB = [&](int buf, int k0) {
#pragma unroll
    for (int ks = 0; ks < 2; ++ks)
#pragma unroll
      for (int i = 0; i < 6; ++i) {
        const int Rb = wn * 96 + i * 16 + lr;
        bfr[buf][ks][i] = *(const s16x8*)&Wcat[(size_t)(n0 + Rb) * D_MODEL +
                                               k0 + ks * 32 + lg * 8];
      }
  };

  stageA(0, 0);
  loadB(0, 0);
  __syncthreads();

  for (int t = 0; t < D_MODEL / 64; ++t) {
    const int cur = t & 1;
    if (t + 1 < D_MODEL / 64) {
      stageA(cur ^ 1, (t + 1) * 64);
      loadB(cur ^ 1, (t + 1) * 64);
    }
    const short* Ac = As + cur * 8192;
#pragma unroll
    for (int ks = 0; ks < 2; ++ks) {
      s16x8 af[4];
#pragma unroll
      for (int i = 0; i < 4; ++i) {
        const int Ra = wm * 64 + i * 16 + lr;
        af[i] = *(const s16x8*)&Ac[Ra * 64 + ((((ks << 2) | lg) ^ (Ra & 7)) << 3)];
      }
      __builtin_amdgcn_s_setprio(1);
#pragma unroll
      for (int mi = 0; mi < 4; ++mi)
#pragma unroll
        for (int ni = 0; ni < 6; ++ni)
          acc[mi][ni] = __builtin_amdgcn_mfma_f32_16x16x32_bf16(
              af[mi], bfr[cur][ks][ni], acc[mi][ni], 0, 0, 0);
      __builtin_amdgcn_s_setprio(0);
    }
    __syncthreads();
  }

#pragma unroll
  for (int ni = 0; ni < 6; ++ni) {
    const int n = n0 + wn * 96 + ni * 16 + lr;
    const int z = n >> 10;              // uniform within a 16-chunk
    const float bn = (z == 0 ? bq[n & 1023] * SC2
                             : (z == 1 ? bk[n & 1023] : bv[n & 1023]));
    short* Cp = z == 0 ? Qb : z == 1 ? Kb : Vtb;
    const int h = (n >> 6) & 15, d = n & 63;
#pragma unroll
    for (int mi = 0; mi < 4; ++mi) {
      const int mb = m0 + wm * 64 + mi * 16 + lg * 4;
      f32x4 v = acc[mi][ni];
      if (z < 2) {
#pragma unroll
        for (int j = 0; j < 4; ++j) {
          int m = mb + j;
          int b = m >> 11, s = m & 2047;
          Cp[((size_t)((b * NHEAD + h) * S_LEN) + s) * HDIM + d] = f2bf(v[j] + bn);
        }
      } else {
        int b = mb >> 11, s = mb & 2047;
        s16x4 p;
#pragma unroll
        for (int j = 0; j < 4; ++j) p[j] = f2bf(v[j] + bn);
        *(s16x4*)&Cp[((size_t)((b * NHEAD + h) * HDIM) + d) * S_LEN + s] = p;
      }
    }
  }
}

// ---------------------------------------------------------------------------
// Output projection: tile 128x64, BK=64, grid 512. B streamed direct (same
// rationale as gemm_qkv). bf16 A (attn out) @ Wto^T + bo -> fp32.
// ---------------------------------------------------------------------------
__global__ __launch_bounds__(256, 2) void gemm_o_k(const short* __restrict__ A,
                                                   const short* __restrict__ Bt,
                                                   const float* __restrict__ bias,
                                                   float* __restrict__ C) {
  __shared__ short As[2 * 128 * 64];   // 32 KB
  const int orig = blockIdx.x;                 // 512 = 64 per XCD
  const int wg = (orig & 7) * 64 + (orig >> 3);
  const int m0 = (wg >> 4) * 128;
  const int n0 = (wg & 15) * 64;

  const int tid = threadIdx.x;
  const int lane = tid & 63, w = tid >> 6;
  const int wm = w >> 1, wn = w & 1;
  const int lr = lane & 15, lg = lane >> 4;
  const int lr8 = lane >> 3;
  const int sl = lane & 7;
  const int scol = ((sl ^ lr8) << 3);

  f32x4 acc[4][2] = {};

  auto stageA = [&](int buf, int k0) {
#pragma unroll
    for (int j = 0; j < 4; ++j) {
      const int rb = j * 4 + w;
      const int row = rb * 8 + lr8;
      gl_lds16(&A[(size_t)(m0 + row) * D_MODEL + k0 + scol],
               &As[buf * 8192 + rb * 512]);
    }
  };

  s16x8 bfr[2][2][2];
  auto loadB = [&](int buf, int k0) {
#pragma unroll
    for (int ks = 0; ks < 2; ++ks)
#pragma unroll
      for (int i = 0; i < 2; ++i) {
        const int Rb = wn * 32 + i * 16 + lr;
        bfr[buf][ks][i] = *(const s16x8*)&Bt[(size_t)(n0 + Rb) * D_MODEL +
                                             k0 + ks * 32 + lg * 8];
      }
  };

  stageA(0, 0);
  loadB(0, 0);
  __syncthreads();

  for (int t = 0; t < D_MODEL / 64; ++t) {
    const int cur = t & 1;
    if (t + 1 < D_MODEL / 64) {
      stageA(cur ^ 1, (t + 1) * 64);
      loadB(cur ^ 1, (t + 1) * 64);
    }
    const short* Ac = As + cur * 8192;
#pragma unroll
    for (int ks = 0; ks < 2; ++ks) {
      s16x8 af[4];
#pragma unroll
      for (int i = 0; i < 4; ++i) {
        const int Ra = wm * 64 + i * 16 + lr;
        af[i] = *(const s16x8*)&Ac[Ra * 64 + ((((ks << 2) | lg) ^ (Ra & 7)) << 3)];
      }
      __builtin_amdgcn_s_setprio(1);
#pragma unroll
      for (int mi = 0; mi < 4; ++mi)
#pragma unroll
        for (int ni = 0; ni < 2; ++ni)
          acc[mi][ni] = __builtin_amdgcn_mfma_f32_16x16x32_bf16(
              af[mi], bfr[cur][ks][ni], acc[mi][ni], 0, 0, 0);
      __builtin_amdgcn_s_setprio(0);
    }
    __syncthreads();
  }

#pragma unroll
  for (int ni = 0; ni < 2; ++ni) {
    const int n = n0 + wn * 32 + ni * 16 + lr;
    const float bn = bias[n];
#pragma unroll
    for (int mi = 0; mi < 4; ++mi) {
      const int mb = m0 + wm * 64 + mi * 16 + lg * 4;
      f32x4 v = acc[mi][ni];
#pragma unroll
      for (int j = 0; j < 4; ++j)
        C[(size_t)(mb + j) * D_MODEL + n] = v[j] + bn;
    }
  }
}

// ---------------------------------------------------------------------------
// Online-softmax helper: per-lane defer-max over 4 score groups.
// ---------------------------------------------------------------------------
__device__ __forceinline__ void softmax4(f32x4 (&sc)[4], float& m_run,
                                         float& l_part, f32x4 (&o)[4],
                                         s16x4 (&pf)[4]) {
  float mg[4];
#pragma unroll
  for (int g = 0; g < 4; ++g)
    mg[g] = fmaxf(fmaxf(sc[g][0], sc[g][1]), fmaxf(sc[g][2], sc[g][3]));
  const float tm = fmaxf(fmaxf(mg[0], mg[1]), fmaxf(mg[2], mg[3]));
  if (!__all(tm <= m_run + 8.f)) {
    float tr = fmaxf(tm, m_run);
    tr = fmaxf(tr, __shfl_xor(tr, 16));
    tr = fmaxf(tr, __shfl_xor(tr, 32));
    const float corr = __builtin_amdgcn_exp2f(m_run - tr);
    l_part *= corr;
#pragma unroll
    for (int dc = 0; dc < 4; ++dc) o[dc] = o[dc] * corr;
    m_run = tr;
  }
#pragma unroll
  for (int g = 0; g < 4; ++g) {
    const float e0 = __builtin_amdgcn_exp2f(sc[g][0] - m_run);
    const float e1 = __builtin_amdgcn_exp2f(sc[g][1] - m_run);
    const float e2 = __builtin_amdgcn_exp2f(sc[g][2] - m_run);
    const float e3 = __builtin_amdgcn_exp2f(sc[g][3] - m_run);
    pf[g] = pk4(e0, e1, e2, e3);
    l_part += (e0 + e1) + (e2 + e3);
  }
}

// ---------------------------------------------------------------------------
// Flash attention (causal). grid 512, 128 q-rows per block, 4 waves.
// Round 9: each wave owns TWO q-fragments (rows r, r+64) and REUSES the
// K/V fragment REGISTERS across both (kf read once -> 2 MFMAs; vf read
// once -> 2 MFMAs). LDS read bytes per q-row HALVE (this was round 7's
// missing mechanism — it re-read K/V per fragment and lost).
// Tiles: t < nt-2 full/full; t == nt-2 A-diag + B-full; t == nt-1 B-diag
// only (A fully masked -> skipped; w-skip on groups).
// Long/short pairing: qt = (bh&1) ? qi : 15-qi. XCD swizzle: 4 heads/XCD.
// ---------------------------------------------------------------------------
__global__ __launch_bounds__(256, 2) void attn_k(const short* __restrict__ Q,
                                                 const short* __restrict__ K,
                                                 const short* __restrict__ Vt,
                                                 short* __restrict__ AO) {
  __shared__ short Ks[2][KVB * HDIM];
  __shared__ short Vs[2][HDIM * KVB];
  const int tid = threadIdx.x, w = tid >> 6, lane = tid & 63;
  const int lr = lane & 15, lg = lane >> 4;
  const int orig = blockIdx.x;                  // 512 = 64 per XCD
  const int wg = (orig & 7) * 64 + (orig >> 3);
  const int bh = wg >> 4;
  const int qi = wg & 15;
  const int qt = (bh & 1) ? qi : 15 - qi;
  const int q0 = qt * 128, nt = 2 * qt + 2;
  const int b = bh >> 4, h = bh & 15;
  const size_t headQK = (size_t)bh * S_LEN * HDIM;
  const size_t headV = (size_t)bh * HDIM * S_LEN;
  const int rowA = q0 + w * 16 + lr;
  const int rowB = rowA + 64;

  const int l8 = lane >> 3, sl = lane & 7;
  const int scol = ((sl ^ l8) << 3);

  auto stage = [&](int kv0, int buf) {
#pragma unroll
    for (int j = 0; j < 2; ++j) {
      const int rb = w * 2 + j;
      const int row = rb * 8 + l8;
      gl_lds16(&K[headQK + (size_t)(kv0 + row) * HDIM + scol],
               &Ks[buf][rb * 512]);
      gl_lds16(&Vt[headV + (size_t)row * S_LEN + kv0 + scol],
               &Vs[buf][rb * 512]);
    }
  };

  const s16x8 qfA0 = *(const s16x8*)&Q[headQK + (size_t)rowA * HDIM + lg * 8];
  const s16x8 qfA1 = *(const s16x8*)&Q[headQK + (size_t)rowA * HDIM + 32 + lg * 8];
  const s16x8 qfB0 = *(const s16x8*)&Q[headQK + (size_t)rowB * HDIM + lg * 8];
  const s16x8 qfB1 = *(const s16x8*)&Q[headQK + (size_t)rowB * HDIM + 32 + lg * 8];

  f32x4 oA[4] = {}, oB[4] = {};
  float mA = -1e30f, mB = -1e30f, lA = 0.f, lB = 0.f;

  stage(0, 0);
  __syncthreads();

  for (int t = 0; t < nt; ++t) {
    if (t + 1 < nt) stage((t + 1) * KVB, (t + 1) & 1);
    const short* Kc = Ks[t & 1];
    const short* Vc = Vs[t & 1];

    if (t < nt - 1) {
      // both fragments active; kf/vf registers shared across A and B
      f32x4 scA[4], scB[4];
      __builtin_amdgcn_s_setprio(1);
#pragma unroll
      for (int g = 0; g < 4; ++g) {
        const int R = g * 16 + lr;
        const s16x8 kf0 = *(const s16x8*)&Kc[R * 64 + ((lg ^ (lr & 7)) << 3)];
        const s16x8 kf1 = *(const s16x8*)&Kc[R * 64 + (((4 | lg) ^ (lr & 7)) << 3)];
        f32x4 z = {0.f, 0.f, 0.f, 0.f};
        scA[g] = __builtin_amdgcn_mfma_f32_16x16x32_bf16(kf0, qfA0, z, 0, 0, 0);
        scB[g] = __builtin_amdgcn_mfma_f32_16x16x32_bf16(kf0, qfB0, z, 0, 0, 0);
        scA[g] = __builtin_amdgcn_mfma_f32_16x16x32_bf16(kf1, qfA1, scA[g], 0, 0, 0);
        scB[g] = __builtin_amdgcn_mfma_f32_16x16x32_bf16(kf1, qfB1, scB[g], 0, 0, 0);
      }
      __builtin_amdgcn_s_setprio(0);

      if (t == nt - 2) {  // diagonal tile for fragment A (kv0 == q0)
#pragma unroll
        for (int g = 0; g < 4; ++g) {
          if (g > w) {
            f32x4 ninf = {-1e30f, -1e30f, -1e30f, -1e30f};
            scA[g] = ninf;
          } else if (g == w) {
#pragma unroll
            for (int j = 0; j < 4; ++j)
              if (lg * 4 + j > lr) scA[g][j] = -1e30f;
          }
        }
      }

      s16x4 pfA[4], pfB[4];
      softmax4(scA, mA, lA, oA, pfA);
      softmax4(scB, mB, lB, oB, pfB);

      __builtin_amdgcn_s_setprio(1);
#pragma unroll
      for (int g = 0; g < 4; ++g)
#pragma unroll
        for (int dc = 0; dc < 4; ++dc) {
          const int row = dc * 16 + lr;
          const s16x4 vf = *(const s16x4*)&Vc[row * 64 +
              (((2 * g + (lg >> 1)) ^ (lr & 7)) << 3) + ((lg & 1) << 2)];
          oA[dc] = __builtin_amdgcn_mfma_f32_16x16x16bf16_1k(vf, pfA[g], oA[dc], 0, 0, 0);
          oB[dc] = __builtin_amdgcn_mfma_f32_16x16x16bf16_1k(vf, pfB[g], oB[dc], 0, 0, 0);
        }
      __builtin_amdgcn_s_setprio(0);
    } else {
      // last tile: fragment B diagonal (A fully masked -> skipped)
      const int gmax = w + 1;   // wave-uniform
      f32x4 scB[4];
      __builtin_amdgcn_s_setprio(1);
#pragma unroll
      for (int g = 0; g < 4; ++g) {
        if (g < gmax) {
          const int R = g * 16 + lr;
          const s16x8 kf0 = *(const s16x8*)&Kc[R * 64 + ((lg ^ (lr & 7)) << 3)];
          const s16x8 kf1 = *(const s16x8*)&Kc[R * 64 + (((4 | lg) ^ (lr & 7)) << 3)];
          f32x4 z = {0.f, 0.f, 0.f, 0.f};
          scB[g] = __builtin_amdgcn_mfma_f32_16x16x32_bf16(kf0, qfB0, z, 0, 0, 0);
          scB[g] = __builtin_amdgcn_mfma_f32_16x16x32_bf16(kf1, qfB1, scB[g], 0, 0, 0);
        }
      }
      __builtin_amdgcn_s_setprio(0);

#pragma unroll
      for (int g = 0; g < 4; ++g)
        if (g == w) {
#pragma unroll
          for (int j = 0; j < 4; ++j)
            if (lg * 4 + j > lr) scB[g][j] = -1e30f;
        }

      float tm = -1e30f;
#pragma unroll
      for (int g = 0; g < 4; ++g)
        if (g < gmax)
          tm = fmaxf(tm, fmaxf(fmaxf(scB[g][0], scB[g][1]),
                               fmaxf(scB[g][2], scB[g][3])));
      if (!__all(tm <= mB + 8.f)) {
        float tr = fmaxf(tm, mB);
        tr = fmaxf(tr, __shfl_xor(tr, 16));
        tr = fmaxf(tr, __shfl_xor(tr, 32));
        const float corr = __builtin_amdgcn_exp2f(mB - tr);
        lB *= corr;
#pragma unroll
        for (int dc = 0; dc < 4; ++dc) oB[dc] = oB[dc] * corr;
        mB = tr;
      }
      s16x4 pfB[4];
#pragma unroll
      for (int g = 0; g < 4; ++g) {
        if (g < gmax) {
          const float e0 = __builtin_amdgcn_exp2f(scB[g][0] - mB);
          const float e1 = __builtin_amdgcn_exp2f(scB[g][1] - mB);
          const float e2 = __builtin_amdgcn_exp2f(scB[g][2] - mB);
          const float e3 = __builtin_amdgcn_exp2f(scB[g][3] - mB);
          pfB[g] = pk4(e0, e1, e2, e3);
          lB += (e0 + e1) + (e2 + e3);
        }
      }
      __builtin_amdgcn_s_setprio(1);
#pragma unroll
      for (int g = 0; g < 4; ++g) {
        if (g < gmax) {
#pragma unroll
          for (int dc = 0; dc < 4; ++dc) {
            const int row = dc * 16 + lr;
            const s16x4 vf = *(const s16x4*)&Vc[row * 64 +
                (((2 * g + (lg >> 1)) ^ (lr & 7)) << 3) + ((lg & 1) << 2)];
            oB[dc] = __builtin_amdgcn_mfma_f32_16x16x16bf16_1k(vf, pfB[g], oB[dc], 0, 0, 0);
          }
        }
      }
      __builtin_amdgcn_s_setprio(0);
    }
    __syncthreads();
  }

  float ltA = lA, ltB = lB;
  ltA += __shfl_xor(ltA, 16); ltA += __shfl_xor(ltA, 32);
  ltB += __shfl_xor(ltB, 16); ltB += __shfl_xor(ltB, 32);
  const float invA = 1.f / ltA, invB = 1.f / ltB;
#pragma unroll
  for (int dc = 0; dc < 4; ++dc) {
    s16x4 pa, pb;
#pragma unroll
    for (int j = 0; j < 4; ++j) {
      pa[j] = f2bf(oA[dc][j] * invA);
      pb[j] = f2bf(oB[dc][j] * invB);
    }
    *(s16x4*)&AO[((size_t)(b * S_LEN + rowA)) * D_MODEL + h * HDIM + dc * 16 + lg * 4] = pa;
    *(s16x4*)&AO[((size_t)(b * S_LEN + rowB)) * D_MODEL + h * HDIM + dc * 16 + lg * 4] = pb;
  }
}

// ---------------------------------------------------------------------------
extern "C" void kernel_launch(void* const* d_in, const int* in_sizes, int n_in,
                              void* d_out, int out_size, void* d_ws, size_t ws_size,
                              hipStream_t stream) {
  const float* X  = (const float*)d_in[0];
  const float* Wq = (const float*)d_in[1];
  const float* bq = (const float*)d_in[2];
  const float* Wk = (const float*)d_in[3];
  const float* bk = (const float*)d_in[4];
  const float* Wv = (const float*)d_in[5];
  const float* bv = (const float*)d_in[6];
  const float* Wo = (const float*)d_in[7];
  const float* bo = (const float*)d_in[8];
  (void)in_sizes; (void)n_in; (void)out_size; (void)ws_size;

  char* ws = (char*)d_ws;
  const size_t WSZ = (size_t)D_MODEL * D_MODEL * sizeof(short);  // 2 MB
  const size_t QSZ = (size_t)M_TOT * D_MODEL * sizeof(short);    // 8 MB
  short* Wcat = (short*)ws;                       // 4 matrices, 8 MB
  short* Qb  = (short*)(ws + 4 * WSZ);
  short* Kb  = (short*)(ws + 4 * WSZ + QSZ);
  short* Vtb = (short*)(ws + 4 * WSZ + 2 * QSZ);
  short* AO  = (short*)(ws + 4 * WSZ + 3 * QSZ);  // doubles as Xb (bf16 X)
  short* Xb  = AO;  // X-cast consumed before attn writes AO
  short* Wto = Wcat + 3 * (size_t)D_MODEL * D_MODEL;

  xcast_k<<<dim3(M_TOT * D_MODEL / 2048), 256, 0, stream>>>(X, Xb);
  wtrans_k<<<dim3(32, 32, 4), dim3(32, 8), 0, stream>>>(Wq, Wk, Wv, Wo, Wcat);

  gemm_qkv_k<<<dim3(512), 256, 0, stream>>>(Xb, Wcat, bq, bk, bv,
                                            Qb, Kb, Vtb);

  attn_k<<<dim3(512), 256, 0, stream>>>(Qb, Kb, Vtb, AO);

  gemm_o_k<<<dim3(512), 256, 0, stream>>>(AO, Wto, bo, (float*)d_out);
}

// Round 10
// 115.834 us; speedup vs baseline: 1.3041x; 1.3041x over previous
//
#include <hip/hip_runtime.h>
#include <hip/hip_bf16.h>

#define S_LEN 2048
#define D_MODEL 1024
#define NHEAD 16
#define HDIM 64
#define BATCH 2
#define M_TOT (BATCH * S_LEN)   // 4096
#define KVB 64

typedef __attribute__((ext_vector_type(4))) float f32x4;
typedef __attribute__((ext_vector_type(4))) short s16x4;
typedef __attribute__((ext_vector_type(8))) short s16x8;

#define AS1 __attribute__((address_space(1)))
#define AS3 __attribute__((address_space(3)))

#define SC2 0.18033688011112042f  // (1/8) * log2(e)

__device__ inline short f2bf(float f) {
  unsigned u = __float_as_uint(f);
  return (short)((u + 0x7fffu + ((u >> 16) & 1u)) >> 16);
}

// HW packed f32->bf16 (RNE). No builtin on gfx950 -> inline asm (T12 recipe).
__device__ __forceinline__ unsigned cvtpk(float lo, float hi) {
  unsigned r;
  asm("v_cvt_pk_bf16_f32 %0, %1, %2" : "=v"(r) : "v"(lo), "v"(hi));
  return r;
}
__device__ __forceinline__ s16x4 pk4(float a, float b, float c, float d) {
  union { unsigned u[2]; s16x4 s; } x;
  x.u[0] = cvtpk(a, b);
  x.u[1] = cvtpk(c, d);
  return x.s;
}

__device__ __forceinline__ void gl_lds16(const short* g, short* l) {
  __builtin_amdgcn_global_load_lds((const AS1 void*)g, (AS3 void*)l, 16, 0, 0);
}

// ---------------------------------------------------------------------------
// X fp32 -> bf16 cast. grid 2048, block 256, 8 elems/thread.
// ---------------------------------------------------------------------------
__global__ __launch_bounds__(256) void xcast_k(const float* __restrict__ X,
                                               short* __restrict__ Xb) {
  const size_t i = ((size_t)blockIdx.x * 256 + threadIdx.x) * 8;
  float4 a = *(const float4*)&X[i];
  float4 b = *(const float4*)&X[i + 4];
  s16x8 p;
  p[0] = f2bf(a.x); p[1] = f2bf(a.y); p[2] = f2bf(a.z); p[3] = f2bf(a.w);
  p[4] = f2bf(b.x); p[5] = f2bf(b.y); p[6] = f2bf(b.z); p[7] = f2bf(b.w);
  *(s16x8*)&Xb[i] = p;
}

// ---------------------------------------------------------------------------
// Weight transpose + cast, all 4 weights into contiguous Wcat[z][n][k].
// Wq (z==0) pre-scaled by (1/8)*log2(e). grid (32,32,4), block (32,8)
// ---------------------------------------------------------------------------
__global__ __launch_bounds__(256) void wtrans_k(const float* __restrict__ W0,
                                                const float* __restrict__ W1,
                                                const float* __restrict__ W2,
                                                const float* __restrict__ W3,
                                                short* __restrict__ Wcat) {
  const int z = blockIdx.z;
  const float* W = z == 0 ? W0 : z == 1 ? W1 : z == 2 ? W2 : W3;
  short* Wt = Wcat + (size_t)z * D_MODEL * D_MODEL;
  const float scl = (z == 0) ? SC2 : 1.f;
  __shared__ float tile[32][33];
  const int tx = threadIdx.x, ty = threadIdx.y;
  const int n0 = blockIdx.x * 32, k0 = blockIdx.y * 32;
#pragma unroll
  for (int j = 0; j < 4; ++j)
    tile[ty + j * 8][tx] = W[(size_t)(k0 + ty + j * 8) * D_MODEL + n0 + tx];
  __syncthreads();
#pragma unroll
  for (int j = 0; j < 4; ++j)
    Wt[(size_t)(n0 + ty + j * 8) * D_MODEL + k0 + tx] =
        f2bf(tile[tx][ty + j * 8] * scl);
}

// ---------------------------------------------------------------------------
// Fused QKV projection: tile 128x192, BK=64, grid 512 (32m x 16n over
// N=3072), 2-phase double-buffered, 80KB LDS = exactly 2 blocks/CU.
// (round-8 version restored — round-9 direct-B streaming regressed)
// ---------------------------------------------------------------------------
__global__ __launch_bounds__(256, 2) void gemm_qkv_k(
    const short* __restrict__ Xb, const short* __restrict__ Wcat,
    const float* __restrict__ bq, const float* __restrict__ bk,
    const float* __restrict__ bv, short* __restrict__ Qb,
    short* __restrict__ Kb, short* __restrict__ Vtb) {
  __shared__ short As[2 * 128 * 64];   // 32 KB
  __shared__ short Bs[2 * 192 * 64];   // 48 KB
  const int orig = blockIdx.x;                 // 512 = 64 per XCD
  const int wg = (orig & 7) * 64 + (orig >> 3);
  const int m0 = (wg >> 4) * 128;              // n-fastest within XCD chunk
  const int n0 = (wg & 15) * 192;

  const int tid = threadIdx.x;
  const int lane = tid & 63, w = tid >> 6;
  const int wm = w >> 1, wn = w & 1;
  const int lr = lane & 15, lg = lane >> 4;
  const int lr8 = lane >> 3;
  const int sl = lane & 7;
  const int scol = ((sl ^ lr8) << 3);

  f32x4 acc[4][6] = {};

  auto stage = [&](int buf, int k0) {
#pragma unroll
    for (int j = 0; j < 4; ++j) {
      const int rb = j * 4 + w;
      const int row = rb * 8 + lr8;
      gl_lds16(&Xb[(size_t)(m0 + row) * D_MODEL + k0 + scol],
               &As[buf * 8192 + rb * 512]);
    }
#pragma unroll
    for (int j = 0; j < 6; ++j) {
      const int rb = j * 4 + w;
      const int row = rb * 8 + lr8;
      gl_lds16(&Wcat[(size_t)(n0 + row) * D_MODEL + k0 + scol],
               &Bs[buf * 12288 + rb * 512]);
    }
  };

  stage(0, 0);
  __syncthreads();

  for (int t = 0; t < D_MODEL / 64; ++t) {
    const int cur = t & 1;
    if (t + 1 < D_MODEL / 64) stage(cur ^ 1, (t + 1) * 64);
    const short* Ac = As + cur * 8192;
    const short* Bc = Bs + cur * 12288;
#pragma unroll
    for (int ks = 0; ks < 2; ++ks) {
      s16x8 af[4], bfr[6];
#pragma unroll
      for (int i = 0; i < 4; ++i) {
        const int Ra = wm * 64 + i * 16 + lr;
        af[i] = *(const s16x8*)&Ac[Ra * 64 + ((((ks << 2) | lg) ^ (Ra & 7)) << 3)];
      }
#pragma unroll
      for (int i = 0; i < 6; ++i) {
        const int Rb = wn * 96 + i * 16 + lr;
        bfr[i] = *(const s16x8*)&Bc[Rb * 64 + ((((ks << 2) | lg) ^ (Rb & 7)) << 3)];
      }
      __builtin_amdgcn_s_setprio(1);
#pragma unroll
      for (int mi = 0; mi < 4; ++mi)
#pragma unroll
        for (int ni = 0; ni < 6; ++ni)
          acc[mi][ni] = __builtin_amdgcn_mfma_f32_16x16x32_bf16(
              af[mi], bfr[ni], acc[mi][ni], 0, 0, 0);
      __builtin_amdgcn_s_setprio(0);
    }
    __syncthreads();
  }

#pragma unroll
  for (int ni = 0; ni < 6; ++ni) {
    const int n = n0 + wn * 96 + ni * 16 + lr;
    const int z = n >> 10;              // uniform within a 16-chunk
    const float bn = (z == 0 ? bq[n & 1023] * SC2
                             : (z == 1 ? bk[n & 1023] : bv[n & 1023]));
    short* Cp = z == 0 ? Qb : z == 1 ? Kb : Vtb;
    const int h = (n >> 6) & 15, d = n & 63;
#pragma unroll
    for (int mi = 0; mi < 4; ++mi) {
      const int mb = m0 + wm * 64 + mi * 16 + lg * 4;
      f32x4 v = acc[mi][ni];
      if (z < 2) {
#pragma unroll
        for (int j = 0; j < 4; ++j) {
          int m = mb + j;
          int b = m >> 11, s = m & 2047;
          Cp[((size_t)((b * NHEAD + h) * S_LEN) + s) * HDIM + d] = f2bf(v[j] + bn);
        }
      } else {
        int b = mb >> 11, s = mb & 2047;
        s16x4 p;
#pragma unroll
        for (int j = 0; j < 4; ++j) p[j] = f2bf(v[j] + bn);
        *(s16x4*)&Cp[((size_t)((b * NHEAD + h) * HDIM) + d) * S_LEN + s] = p;
      }
    }
  }
}

// ---------------------------------------------------------------------------
// Output projection: tile 128x64, BK=64, grid 512. (round-8 version restored)
// ---------------------------------------------------------------------------
__global__ __launch_bounds__(256, 2) void gemm_o_k(const short* __restrict__ A,
                                                   const short* __restrict__ Bt,
                                                   const float* __restrict__ bias,
                                                   float* __restrict__ C) {
  __shared__ short As[2 * 128 * 64];   // 32 KB
  __shared__ short Bs[2 * 64 * 64];    // 16 KB
  const int orig = blockIdx.x;                 // 512 = 64 per XCD
  const int wg = (orig & 7) * 64 + (orig >> 3);
  const int m0 = (wg >> 4) * 128;
  const int n0 = (wg & 15) * 64;

  const int tid = threadIdx.x;
  const int lane = tid & 63, w = tid >> 6;
  const int wm = w >> 1, wn = w & 1;
  const int lr = lane & 15, lg = lane >> 4;
  const int lr8 = lane >> 3;
  const int sl = lane & 7;
  const int scol = ((sl ^ lr8) << 3);

  f32x4 acc[4][2] = {};

  auto stage = [&](int buf, int k0) {
#pragma unroll
    for (int j = 0; j < 4; ++j) {
      const int rb = j * 4 + w;
      const int row = rb * 8 + lr8;
      gl_lds16(&A[(size_t)(m0 + row) * D_MODEL + k0 + scol],
               &As[buf * 8192 + rb * 512]);
    }
#pragma unroll
    for (int j = 0; j < 2; ++j) {
      const int rb = j * 4 + w;
      const int row = rb * 8 + lr8;
      gl_lds16(&Bt[(size_t)(n0 + row) * D_MODEL + k0 + scol],
               &Bs[buf * 4096 + rb * 512]);
    }
  };

  stage(0, 0);
  __syncthreads();

  for (int t = 0; t < D_MODEL / 64; ++t) {
    const int cur = t & 1;
    if (t + 1 < D_MODEL / 64) stage(cur ^ 1, (t + 1) * 64);
    const short* Ac = As + cur * 8192;
    const short* Bc = Bs + cur * 4096;
#pragma unroll
    for (int ks = 0; ks < 2; ++ks) {
      s16x8 af[4], bfr[2];
#pragma unroll
      for (int i = 0; i < 4; ++i) {
        const int Ra = wm * 64 + i * 16 + lr;
        af[i] = *(const s16x8*)&Ac[Ra * 64 + ((((ks << 2) | lg) ^ (Ra & 7)) << 3)];
      }
#pragma unroll
      for (int i = 0; i < 2; ++i) {
        const int Rb = wn * 32 + i * 16 + lr;
        bfr[i] = *(const s16x8*)&Bc[Rb * 64 + ((((ks << 2) | lg) ^ (Rb & 7)) << 3)];
      }
      __builtin_amdgcn_s_setprio(1);
#pragma unroll
      for (int mi = 0; mi < 4; ++mi)
#pragma unroll
        for (int ni = 0; ni < 2; ++ni)
          acc[mi][ni] = __builtin_amdgcn_mfma_f32_16x16x32_bf16(
              af[mi], bfr[cur & 0 ? ni : ni], acc[mi][ni], 0, 0, 0);
      __builtin_amdgcn_s_setprio(0);
    }
    __syncthreads();
  }

#pragma unroll
  for (int ni = 0; ni < 2; ++ni) {
    const int n = n0 + wn * 32 + ni * 16 + lr;
    const float bn = bias[n];
#pragma unroll
    for (int mi = 0; mi < 4; ++mi) {
      const int mb = m0 + wm * 64 + mi * 16 + lg * 4;
      f32x4 v = acc[mi][ni];
#pragma unroll
      for (int j = 0; j < 4; ++j)
        C[(size_t)(mb + j) * D_MODEL + n] = v[j] + bn;
    }
  }
}

// ---------------------------------------------------------------------------
// Flash attention (causal) — round-8 structure, round-10 balance fix.
// grid 1024, one 64-row q-tile per block, 4 waves, 4 blocks/CU.
// With 1024 blocks and exactly 4 blocks/CU, ALL blocks are co-resident:
// the static assignment IS the schedule. Round-8's qt map gave each CU 4
// SIMILAR-length blocks (per-CU work 10..118 units, avg 66) -> duration
// tracked the max. Fix: alternate long/short per consecutive qi so any
// 4-window sums ~62: qt = (qi&1) ? qi>>1 : 31-(qi>>1)  (bijective).
// ---------------------------------------------------------------------------
__global__ __launch_bounds__(256, 4) void attn_k(const short* __restrict__ Q,
                                                 const short* __restrict__ K,
                                                 const short* __restrict__ Vt,
                                                 short* __restrict__ AO) {
  __shared__ short Ks[2][KVB * HDIM];
  __shared__ short Vs[2][HDIM * KVB];
  const int tid = threadIdx.x, w = tid >> 6, lane = tid & 63;
  const int lr = lane & 15, lg = lane >> 4;
  const int orig = blockIdx.x;
  const int wg = (orig & 7) * 128 + (orig >> 3);
  const int bh = wg >> 5, qi = wg & 31;
  const int qt = (qi & 1) ? (qi >> 1) : 31 - (qi >> 1);  // balance fix
  const int q0 = qt * 64, nt = qt + 1;
  const int b = bh >> 4, h = bh & 15;
  const size_t headQK = (size_t)bh * S_LEN * HDIM;
  const size_t headV = (size_t)bh * HDIM * S_LEN;
  const int qrow = q0 + w * 16 + lr;

  const int l8 = lane >> 3, sl = lane & 7;
  const int scol = ((sl ^ l8) << 3);

  auto stage = [&](int kv0, int buf) {
#pragma unroll
    for (int j = 0; j < 2; ++j) {
      const int rb = w * 2 + j;
      const int row = rb * 8 + l8;
      gl_lds16(&K[headQK + (size_t)(kv0 + row) * HDIM + scol],
               &Ks[buf][rb * 512]);
      gl_lds16(&Vt[headV + (size_t)row * S_LEN + kv0 + scol],
               &Vs[buf][rb * 512]);
    }
  };

  const s16x8 qf0 = *(const s16x8*)&Q[headQK + (size_t)qrow * HDIM + lg * 8];
  const s16x8 qf1 = *(const s16x8*)&Q[headQK + (size_t)qrow * HDIM + 32 + lg * 8];

  f32x4 o[4] = {};
  float m_run = -1e30f;
  float l_part = 0.f;   // per-lane partial; cross-lane reduced once at end

  stage(0, 0);
  __syncthreads();

  for (int t = 0; t < nt; ++t) {
    if (t + 1 < nt) stage((t + 1) * KVB, (t + 1) & 1);
    const short* Kc = Ks[t & 1];
    const short* Vc = Vs[t & 1];
    const bool diag = (t == nt - 1);
    const int gmax = diag ? (w + 1) : 4;   // wave-uniform

    // scores^T (already scaled to log2 domain): S^T = K @ Q'^T
    f32x4 sc[4];
    __builtin_amdgcn_s_setprio(1);
#pragma unroll
    for (int g = 0; g < 4; ++g) {
      if (g < gmax) {
        const int R = g * 16 + lr;
        const s16x8 kf0 = *(const s16x8*)&Kc[R * 64 + ((lg ^ (lr & 7)) << 3)];
        const s16x8 kf1 = *(const s16x8*)&Kc[R * 64 + (((4 | lg) ^ (lr & 7)) << 3)];
        f32x4 z = {0.f, 0.f, 0.f, 0.f};
        sc[g] = __builtin_amdgcn_mfma_f32_16x16x32_bf16(kf0, qf0, z, 0, 0, 0);
        sc[g] = __builtin_amdgcn_mfma_f32_16x16x32_bf16(kf1, qf1, sc[g], 0, 0, 0);
      }
    }
    __builtin_amdgcn_s_setprio(0);

    if (diag) {  // element mask only needed for the partial group g == w
#pragma unroll
      for (int g = 0; g < 4; ++g)
        if (g == w) {
#pragma unroll
          for (int j = 0; j < 4; ++j)
            if (lg * 4 + j > lr) sc[g][j] = -1e30f;
        }
    }

    // per-lane max over active groups
    float tm = -1e30f;
#pragma unroll
    for (int g = 0; g < 4; ++g)
      if (g < gmax)
        tm = fmaxf(tm, fmaxf(fmaxf(sc[g][0], sc[g][1]),
                             fmaxf(sc[g][2], sc[g][3])));

    // defer-max: full row-max reduce + rescale only when some row grew >THR=8
    if (!__all(tm <= m_run + 8.f)) {
      float tr = fmaxf(tm, m_run);
      tr = fmaxf(tr, __shfl_xor(tr, 16));
      tr = fmaxf(tr, __shfl_xor(tr, 32));
      const float corr = __builtin_amdgcn_exp2f(m_run - tr);
      l_part *= corr;
#pragma unroll
      for (int dc = 0; dc < 4; ++dc) o[dc] = o[dc] * corr;
      m_run = tr;
    }

    // P = exp2(sc - m_run), pack via HW cvt_pk, accumulate per-lane l
    s16x4 pf[4];
#pragma unroll
    for (int g = 0; g < 4; ++g) {
      if (g < gmax) {
        const float e0 = __builtin_amdgcn_exp2f(sc[g][0] - m_run);
        const float e1 = __builtin_amdgcn_exp2f(sc[g][1] - m_run);
        const float e2 = __builtin_amdgcn_exp2f(sc[g][2] - m_run);
        const float e3 = __builtin_amdgcn_exp2f(sc[g][3] - m_run);
        pf[g] = pk4(e0, e1, e2, e3);
        l_part += (e0 + e1) + (e2 + e3);
      }
    }

    __builtin_amdgcn_s_setprio(1);
#pragma unroll
    for (int g = 0; g < 4; ++g) {
      if (g < gmax) {
#pragma unroll
        for (int dc = 0; dc < 4; ++dc) {
          const int row = dc * 16 + lr;
          const s16x4 vf = *(const s16x4*)&Vc[row * 64 +
              (((2 * g + (lg >> 1)) ^ (lr & 7)) << 3) + ((lg & 1) << 2)];
          o[dc] = __builtin_amdgcn_mfma_f32_16x16x16bf16_1k(vf, pf[g], o[dc], 0, 0, 0);
        }
      }
    }
    __builtin_amdgcn_s_setprio(0);
    __syncthreads();
  }

  // single end-of-tile cross-lane reduce of the partial l (lanes of same row)
  float lt = l_part;
  lt += __shfl_xor(lt, 16);
  lt += __shfl_xor(lt, 32);
  const float inv = 1.f / lt;
#pragma unroll
  for (int dc = 0; dc < 4; ++dc) {
    s16x4 pk;
#pragma unroll
    for (int j = 0; j < 4; ++j) pk[j] = f2bf(o[dc][j] * inv);
    *(s16x4*)&AO[((size_t)(b * S_LEN + qrow)) * D_MODEL + h * HDIM + dc * 16 + lg * 4] = pk;
  }
}

// ---------------------------------------------------------------------------
extern "C" void kernel_launch(void* const* d_in, const int* in_sizes, int n_in,
                              void* d_out, int out_size, void* d_ws, size_t ws_size,
                              hipStream_t stream) {
  const float* X  = (const float*)d_in[0];
  const float* Wq = (const float*)d_in[1];
  const float* bq = (const float*)d_in[2];
  const float* Wk = (const float*)d_in[3];
  const float* bk = (const float*)d_in[4];
  const float* Wv = (const float*)d_in[5];
  const float* bv = (const float*)d_in[6];
  const float* Wo = (const float*)d_in[7];
  const float* bo = (const float*)d_in[8];
  (void)in_sizes; (void)n_in; (void)out_size; (void)ws_size;

  char* ws = (char*)d_ws;
  const size_t WSZ = (size_t)D_MODEL * D_MODEL * sizeof(short);  // 2 MB
  const size_t QSZ = (size_t)M_TOT * D_MODEL * sizeof(short);    // 8 MB
  short* Wcat = (short*)ws;                       // 4 matrices, 8 MB
  short* Qb  = (short*)(ws + 4 * WSZ);
  short* Kb  = (short*)(ws + 4 * WSZ + QSZ);
  short* Vtb = (short*)(ws + 4 * WSZ + 2 * QSZ);
  short* AO  = (short*)(ws + 4 * WSZ + 3 * QSZ);  // doubles as Xb (bf16 X)
  short* Xb  = AO;  // X-cast consumed before attn writes AO
  short* Wto = Wcat + 3 * (size_t)D_MODEL * D_MODEL;

  xcast_k<<<dim3(M_TOT * D_MODEL / 2048), 256, 0, stream>>>(X, Xb);
  wtrans_k<<<dim3(32, 32, 4), dim3(32, 8), 0, stream>>>(Wq, Wk, Wv, Wo, Wcat);

  gemm_qkv_k<<<dim3(512), 256, 0, stream>>>(Xb, Wcat, bq, bk, bv,
                                            Qb, Kb, Vtb);

  attn_k<<<dim3(1024), 256, 0, stream>>>(Qb, Kb, Vtb, AO);

  gemm_o_k<<<dim3(512), 256, 0, stream>>>(AO, Wto, bo, (float*)d_out);
}

// Round 11
// 105.710 us; speedup vs baseline: 1.4290x; 1.0958x over previous
//
#include <hip/hip_runtime.h>
#include <hip/hip_bf16.h>

#define S_LEN 2048
#define D_MODEL 1024
#define NHEAD 16
#define HDIM 64
#define BATCH 2
#define M_TOT (BATCH * S_LEN)   // 4096
#define KVB 64

typedef __attribute__((ext_vector_type(4))) float f32x4;
typedef __attribute__((ext_vector_type(4))) short s16x4;
typedef __attribute__((ext_vector_type(8))) short s16x8;

#define AS1 __attribute__((address_space(1)))
#define AS3 __attribute__((address_space(3)))

#define SC2 0.18033688011112042f  // (1/8) * log2(e)

__device__ inline short f2bf(float f) {
  unsigned u = __float_as_uint(f);
  return (short)((u + 0x7fffu + ((u >> 16) & 1u)) >> 16);
}

// HW packed f32->bf16 (RNE). No builtin on gfx950 -> inline asm (T12 recipe).
__device__ __forceinline__ unsigned cvtpk(float lo, float hi) {
  unsigned r;
  asm("v_cvt_pk_bf16_f32 %0, %1, %2" : "=v"(r) : "v"(lo), "v"(hi));
  return r;
}
__device__ __forceinline__ s16x4 pk4(float a, float b, float c, float d) {
  union { unsigned u[2]; s16x4 s; } x;
  x.u[0] = cvtpk(a, b);
  x.u[1] = cvtpk(c, d);
  return x.s;
}

__device__ __forceinline__ void gl_lds16(const short* g, short* l) {
  __builtin_amdgcn_global_load_lds((const AS1 void*)g, (AS3 void*)l, 16, 0, 0);
}

// ---------------------------------------------------------------------------
// X fp32 -> bf16 cast. grid 2048, block 256, 8 elems/thread.
// ---------------------------------------------------------------------------
__global__ __launch_bounds__(256) void xcast_k(const float* __restrict__ X,
                                               short* __restrict__ Xb) {
  const size_t i = ((size_t)blockIdx.x * 256 + threadIdx.x) * 8;
  float4 a = *(const float4*)&X[i];
  float4 b = *(const float4*)&X[i + 4];
  s16x8 p;
  p[0] = f2bf(a.x); p[1] = f2bf(a.y); p[2] = f2bf(a.z); p[3] = f2bf(a.w);
  p[4] = f2bf(b.x); p[5] = f2bf(b.y); p[6] = f2bf(b.z); p[7] = f2bf(b.w);
  *(s16x8*)&Xb[i] = p;
}

// ---------------------------------------------------------------------------
// Weight transpose + cast, all 4 weights into contiguous Wcat[z][n][k].
// Wq (z==0) pre-scaled by (1/8)*log2(e). grid (32,32,4), block (32,8)
// ---------------------------------------------------------------------------
__global__ __launch_bounds__(256) void wtrans_k(const float* __restrict__ W0,
                                                const float* __restrict__ W1,
                                                const float* __restrict__ W2,
                                                const float* __restrict__ W3,
                                                short* __restrict__ Wcat) {
  const int z = blockIdx.z;
  const float* W = z == 0 ? W0 : z == 1 ? W1 : z == 2 ? W2 : W3;
  short* Wt = Wcat + (size_t)z * D_MODEL * D_MODEL;
  const float scl = (z == 0) ? SC2 : 1.f;
  __shared__ float tile[32][33];
  const int tx = threadIdx.x, ty = threadIdx.y;
  const int n0 = blockIdx.x * 32, k0 = blockIdx.y * 32;
#pragma unroll
  for (int j = 0; j < 4; ++j)
    tile[ty + j * 8][tx] = W[(size_t)(k0 + ty + j * 8) * D_MODEL + n0 + tx];
  __syncthreads();
#pragma unroll
  for (int j = 0; j < 4; ++j)
    Wt[(size_t)(n0 + ty + j * 8) * D_MODEL + k0 + tx] =
        f2bf(tile[tx][ty + j * 8] * scl);
}

// ---------------------------------------------------------------------------
// Fused QKV projection: tile 128x192, BK=64, grid 512, 2-phase dbuf, 80KB
// LDS = 2 blocks/CU. Round 11: XCD-CHUNKED mapping — all 64 blocks of an
// XCD are co-resident, so the XCD's L2 working set is the chunk footprint.
// 8m x 8n chunk: A 2MB + B 3MB ~ L2-resident (was 1+6 = 7MB > 4MB -> thrash,
// FETCH 28.8MB). Chunk grid 4x2 = 8 = one per XCD, bijective.
// ---------------------------------------------------------------------------
__global__ __launch_bounds__(256, 2) void gemm_qkv_k(
    const short* __restrict__ Xb, const short* __restrict__ Wcat,
    const float* __restrict__ bq, const float* __restrict__ bk,
    const float* __restrict__ bv, short* __restrict__ Qb,
    short* __restrict__ Kb, short* __restrict__ Vtb) {
  __shared__ short As[2 * 128 * 64];   // 32 KB
  __shared__ short Bs[2 * 192 * 64];   // 48 KB
  const int orig = blockIdx.x;                 // 512
  const int xcd = orig & 7;                    // chunk = XCD
  const int k = orig >> 3;                     // 0..63 within chunk
  const int m0 = (((xcd & 3) << 3) + (k & 7)) * 128;   // 4 chunk-cols of m
  const int n0 = (((xcd >> 2) << 3) + (k >> 3)) * 192; // 2 chunk-rows of n

  const int tid = threadIdx.x;
  const int lane = tid & 63, w = tid >> 6;
  const int wm = w >> 1, wn = w & 1;
  const int lr = lane & 15, lg = lane >> 4;
  const int lr8 = lane >> 3;
  const int sl = lane & 7;
  const int scol = ((sl ^ lr8) << 3);

  f32x4 acc[4][6] = {};

  auto stage = [&](int buf, int k0) {
#pragma unroll
    for (int j = 0; j < 4; ++j) {
      const int rb = j * 4 + w;
      const int row = rb * 8 + lr8;
      gl_lds16(&Xb[(size_t)(m0 + row) * D_MODEL + k0 + scol],
               &As[buf * 8192 + rb * 512]);
    }
#pragma unroll
    for (int j = 0; j < 6; ++j) {
      const int rb = j * 4 + w;
      const int row = rb * 8 + lr8;
      gl_lds16(&Wcat[(size_t)(n0 + row) * D_MODEL + k0 + scol],
               &Bs[buf * 12288 + rb * 512]);
    }
  };

  stage(0, 0);
  __syncthreads();

  for (int t = 0; t < D_MODEL / 64; ++t) {
    const int cur = t & 1;
    if (t + 1 < D_MODEL / 64) stage(cur ^ 1, (t + 1) * 64);
    const short* Ac = As + cur * 8192;
    const short* Bc = Bs + cur * 12288;
#pragma unroll
    for (int ks = 0; ks < 2; ++ks) {
      s16x8 af[4], bfr[6];
#pragma unroll
      for (int i = 0; i < 4; ++i) {
        const int Ra = wm * 64 + i * 16 + lr;
        af[i] = *(const s16x8*)&Ac[Ra * 64 + ((((ks << 2) | lg) ^ (Ra & 7)) << 3)];
      }
#pragma unroll
      for (int i = 0; i < 6; ++i) {
        const int Rb = wn * 96 + i * 16 + lr;
        bfr[i] = *(const s16x8*)&Bc[Rb * 64 + ((((ks << 2) | lg) ^ (Rb & 7)) << 3)];
      }
      __builtin_amdgcn_s_setprio(1);
#pragma unroll
      for (int mi = 0; mi < 4; ++mi)
#pragma unroll
        for (int ni = 0; ni < 6; ++ni)
          acc[mi][ni] = __builtin_amdgcn_mfma_f32_16x16x32_bf16(
              af[mi], bfr[ni], acc[mi][ni], 0, 0, 0);
      __builtin_amdgcn_s_setprio(0);
    }
    __syncthreads();
  }

#pragma unroll
  for (int ni = 0; ni < 6; ++ni) {
    const int n = n0 + wn * 96 + ni * 16 + lr;
    const int z = n >> 10;              // uniform within a 16-chunk
    const float bn = (z == 0 ? bq[n & 1023] * SC2
                             : (z == 1 ? bk[n & 1023] : bv[n & 1023]));
    short* Cp = z == 0 ? Qb : z == 1 ? Kb : Vtb;
    const int h = (n >> 6) & 15, d = n & 63;
#pragma unroll
    for (int mi = 0; mi < 4; ++mi) {
      const int mb = m0 + wm * 64 + mi * 16 + lg * 4;
      f32x4 v = acc[mi][ni];
      if (z < 2) {
#pragma unroll
        for (int j = 0; j < 4; ++j) {
          int m = mb + j;
          int b = m >> 11, s = m & 2047;
          Cp[((size_t)((b * NHEAD + h) * S_LEN) + s) * HDIM + d] = f2bf(v[j] + bn);
        }
      } else {
        int b = mb >> 11, s = mb & 2047;
        s16x4 p;
#pragma unroll
        for (int j = 0; j < 4; ++j) p[j] = f2bf(v[j] + bn);
        *(s16x4*)&Cp[((size_t)((b * NHEAD + h) * HDIM) + d) * S_LEN + s] = p;
      }
    }
  }
}

// ---------------------------------------------------------------------------
// Output projection: tile 128x64, BK=64, grid 512 (32m x 16n), XCD-chunked
// 8x8 mapping (A 2MB + B 1MB per XCD, L2-resident).
// ---------------------------------------------------------------------------
__global__ __launch_bounds__(256, 2) void gemm_o_k(const short* __restrict__ A,
                                                   const short* __restrict__ Bt,
                                                   const float* __restrict__ bias,
                                                   float* __restrict__ C) {
  __shared__ short As[2 * 128 * 64];   // 32 KB
  __shared__ short Bs[2 * 64 * 64];    // 16 KB
  const int orig = blockIdx.x;                 // 512
  const int xcd = orig & 7;
  const int k = orig >> 3;
  const int m0 = (((xcd & 3) << 3) + (k & 7)) * 128;
  const int n0 = (((xcd >> 2) << 3) + (k >> 3)) * 64;

  const int tid = threadIdx.x;
  const int lane = tid & 63, w = tid >> 6;
  const int wm = w >> 1, wn = w & 1;
  const int lr = lane & 15, lg = lane >> 4;
  const int lr8 = lane >> 3;
  const int sl = lane & 7;
  const int scol = ((sl ^ lr8) << 3);

  f32x4 acc[4][2] = {};

  auto stage = [&](int buf, int k0) {
#pragma unroll
    for (int j = 0; j < 4; ++j) {
      const int rb = j * 4 + w;
      const int row = rb * 8 + lr8;
      gl_lds16(&A[(size_t)(m0 + row) * D_MODEL + k0 + scol],
               &As[buf * 8192 + rb * 512]);
    }
#pragma unroll
    for (int j = 0; j < 2; ++j) {
      const int rb = j * 4 + w;
      const int row = rb * 8 + lr8;
      gl_lds16(&Bt[(size_t)(n0 + row) * D_MODEL + k0 + scol],
               &Bs[buf * 4096 + rb * 512]);
    }
  };

  stage(0, 0);
  __syncthreads();

  for (int t = 0; t < D_MODEL / 64; ++t) {
    const int cur = t & 1;
    if (t + 1 < D_MODEL / 64) stage(cur ^ 1, (t + 1) * 64);
    const short* Ac = As + cur * 8192;
    const short* Bc = Bs + cur * 4096;
#pragma unroll
    for (int ks = 0; ks < 2; ++ks) {
      s16x8 af[4], bfr[2];
#pragma unroll
      for (int i = 0; i < 4; ++i) {
        const int Ra = wm * 64 + i * 16 + lr;
        af[i] = *(const s16x8*)&Ac[Ra * 64 + ((((ks << 2) | lg) ^ (Ra & 7)) << 3)];
      }
#pragma unroll
      for (int i = 0; i < 2; ++i) {
        const int Rb = wn * 32 + i * 16 + lr;
        bfr[i] = *(const s16x8*)&Bc[Rb * 64 + ((((ks << 2) | lg) ^ (Rb & 7)) << 3)];
      }
      __builtin_amdgcn_s_setprio(1);
#pragma unroll
      for (int mi = 0; mi < 4; ++mi)
#pragma unroll
        for (int ni = 0; ni < 2; ++ni)
          acc[mi][ni] = __builtin_amdgcn_mfma_f32_16x16x32_bf16(
              af[mi], bfr[ni], acc[mi][ni], 0, 0, 0);
      __builtin_amdgcn_s_setprio(0);
    }
    __syncthreads();
  }

#pragma unroll
  for (int ni = 0; ni < 2; ++ni) {
    const int n = n0 + wn * 32 + ni * 16 + lr;
    const float bn = bias[n];
#pragma unroll
    for (int mi = 0; mi < 4; ++mi) {
      const int mb = m0 + wm * 64 + mi * 16 + lg * 4;
      f32x4 v = acc[mi][ni];
#pragma unroll
      for (int j = 0; j < 4; ++j)
        C[(size_t)(mb + j) * D_MODEL + n] = v[j] + bn;
    }
  }
}

// ---------------------------------------------------------------------------
// Flash attention (causal) — exact round-8 structure and mapping.
// Under round-robin dispatch, CU c of XCD x hosts blocks k in {c,c+32,c+64,
// c+96}: same qi, 4 consecutive bh (2 even, 2 odd) -> per-CU work
// 2(qi+1)+2(32-qi) = 66 units, balanced BY CONSTRUCTION via the bh-parity
// map qt=(bh&1)?qi:31-qi. (Round-10's qi-based map broke this: all 4 blocks
// on a CU shared one qt -> 4..128 units/CU -> 62µs. Measured, understood.)
// ---------------------------------------------------------------------------
__global__ __launch_bounds__(256, 4) void attn_k(const short* __restrict__ Q,
                                                 const short* __restrict__ K,
                                                 const short* __restrict__ Vt,
                                                 short* __restrict__ AO) {
  __shared__ short Ks[2][KVB * HDIM];
  __shared__ short Vs[2][HDIM * KVB];
  const int tid = threadIdx.x, w = tid >> 6, lane = tid & 63;
  const int lr = lane & 15, lg = lane >> 4;
  const int orig = blockIdx.x;
  const int wg = (orig & 7) * 128 + (orig >> 3);
  const int bh = wg >> 5, qi = wg & 31;
  const int qt = (bh & 1) ? qi : 31 - qi;   // round-8 balanced map
  const int q0 = qt * 64, nt = qt + 1;
  const int b = bh >> 4, h = bh & 15;
  const size_t headQK = (size_t)bh * S_LEN * HDIM;
  const size_t headV = (size_t)bh * HDIM * S_LEN;
  const int qrow = q0 + w * 16 + lr;

  const int l8 = lane >> 3, sl = lane & 7;
  const int scol = ((sl ^ l8) << 3);

  auto stage = [&](int kv0, int buf) {
#pragma unroll
    for (int j = 0; j < 2; ++j) {
      const int rb = w * 2 + j;
      const int row = rb * 8 + l8;
      gl_lds16(&K[headQK + (size_t)(kv0 + row) * HDIM + scol],
               &Ks[buf][rb * 512]);
      gl_lds16(&Vt[headV + (size_t)row * S_LEN + kv0 + scol],
               &Vs[buf][rb * 512]);
    }
  };

  const s16x8 qf0 = *(const s16x8*)&Q[headQK + (size_t)qrow * HDIM + lg * 8];
  const s16x8 qf1 = *(const s16x8*)&Q[headQK + (size_t)qrow * HDIM + 32 + lg * 8];

  f32x4 o[4] = {};
  float m_run = -1e30f;
  float l_part = 0.f;   // per-lane partial; cross-lane reduced once at end

  stage(0, 0);
  __syncthreads();

  for (int t = 0; t < nt; ++t) {
    if (t + 1 < nt) stage((t + 1) * KVB, (t + 1) & 1);
    const short* Kc = Ks[t & 1];
    const short* Vc = Vs[t & 1];
    const bool diag = (t == nt - 1);
    const int gmax = diag ? (w + 1) : 4;   // wave-uniform

    // scores^T (already scaled to log2 domain): S^T = K @ Q'^T
    f32x4 sc[4];
    __builtin_amdgcn_s_setprio(1);
#pragma unroll
    for (int g = 0; g < 4; ++g) {
      if (g < gmax) {
        const int R = g * 16 + lr;
        const s16x8 kf0 = *(const s16x8*)&Kc[R * 64 + ((lg ^ (lr & 7)) << 3)];
        const s16x8 kf1 = *(const s16x8*)&Kc[R * 64 + (((4 | lg) ^ (lr & 7)) << 3)];
        f32x4 z = {0.f, 0.f, 0.f, 0.f};
        sc[g] = __builtin_amdgcn_mfma_f32_16x16x32_bf16(kf0, qf0, z, 0, 0, 0);
        sc[g] = __builtin_amdgcn_mfma_f32_16x16x32_bf16(kf1, qf1, sc[g], 0, 0, 0);
      }
    }
    __builtin_amdgcn_s_setprio(0);

    if (diag) {  // element mask only needed for the partial group g == w
#pragma unroll
      for (int g = 0; g < 4; ++g)
        if (g == w) {
#pragma unroll
          for (int j = 0; j < 4; ++j)
            if (lg * 4 + j > lr) sc[g][j] = -1e30f;
        }
    }

    // per-lane max over active groups
    float tm = -1e30f;
#pragma unroll
    for (int g = 0; g < 4; ++g)
      if (g < gmax)
        tm = fmaxf(tm, fmaxf(fmaxf(sc[g][0], sc[g][1]),
                             fmaxf(sc[g][2], sc[g][3])));

    // defer-max: full row-max reduce + rescale only when some row grew >THR=8
    if (!__all(tm <= m_run + 8.f)) {
      float tr = fmaxf(tm, m_run);
      tr = fmaxf(tr, __shfl_xor(tr, 16));
      tr = fmaxf(tr, __shfl_xor(tr, 32));
      const float corr = __builtin_amdgcn_exp2f(m_run - tr);
      l_part *= corr;
#pragma unroll
      for (int dc = 0; dc < 4; ++dc) o[dc] = o[dc] * corr;
      m_run = tr;
    }

    // P = exp2(sc - m_run), pack via HW cvt_pk, accumulate per-lane l
    s16x4 pf[4];
#pragma unroll
    for (int g = 0; g < 4; ++g) {
      if (g < gmax) {
        const float e0 = __builtin_amdgcn_exp2f(sc[g][0] - m_run);
        const float e1 = __builtin_amdgcn_exp2f(sc[g][1] - m_run);
        const float e2 = __builtin_amdgcn_exp2f(sc[g][2] - m_run);
        const float e3 = __builtin_amdgcn_exp2f(sc[g][3] - m_run);
        pf[g] = pk4(e0, e1, e2, e3);
        l_part += (e0 + e1) + (e2 + e3);
      }
    }

    __builtin_amdgcn_s_setprio(1);
#pragma unroll
    for (int g = 0; g < 4; ++g) {
      if (g < gmax) {
#pragma unroll
        for (int dc = 0; dc < 4; ++dc) {
          const int row = dc * 16 + lr;
          const s16x4 vf = *(const s16x4*)&Vc[row * 64 +
              (((2 * g + (lg >> 1)) ^ (lr & 7)) << 3) + ((lg & 1) << 2)];
          o[dc] = __builtin_amdgcn_mfma_f32_16x16x16bf16_1k(vf, pf[g], o[dc], 0, 0, 0);
        }
      }
    }
    __builtin_amdgcn_s_setprio(0);
    __syncthreads();
  }

  // single end-of-tile cross-lane reduce of the partial l (lanes of same row)
  float lt = l_part;
  lt += __shfl_xor(lt, 16);
  lt += __shfl_xor(lt, 32);
  const float inv = 1.f / lt;
#pragma unroll
  for (int dc = 0; dc < 4; ++dc) {
    s16x4 pk;
#pragma unroll
    for (int j = 0; j < 4; ++j) pk[j] = f2bf(o[dc][j] * inv);
    *(s16x4*)&AO[((size_t)(b * S_LEN + qrow)) * D_MODEL + h * HDIM + dc * 16 + lg * 4] = pk;
  }
}

// ---------------------------------------------------------------------------
extern "C" void kernel_launch(void* const* d_in, const int* in_sizes, int n_in,
                              void* d_out, int out_size, void* d_ws, size_t ws_size,
                              hipStream_t stream) {
  const float* X  = (const float*)d_in[0];
  const float* Wq = (const float*)d_in[1];
  const float* bq = (const float*)d_in[2];
  const float* Wk = (const float*)d_in[3];
  const float* bk = (const float*)d_in[4];
  const float* Wv = (const float*)d_in[5];
  const float* bv = (const float*)d_in[6];
  const float* Wo = (const float*)d_in[7];
  const float* bo = (const float*)d_in[8];
  (void)in_sizes; (void)n_in; (void)out_size; (void)ws_size;

  char* ws = (char*)d_ws;
  const size_t WSZ = (size_t)D_MODEL * D_MODEL * sizeof(short);  // 2 MB
  const size_t QSZ = (size_t)M_TOT * D_MODEL * sizeof(short);    // 8 MB
  short* Wcat = (short*)ws;                       // 4 matrices, 8 MB
  short* Qb  = (short*)(ws + 4 * WSZ);
  short* Kb  = (short*)(ws + 4 * WSZ + QSZ);
  short* Vtb = (short*)(ws + 4 * WSZ + 2 * QSZ);
  short* AO  = (short*)(ws + 4 * WSZ + 3 * QSZ);  // doubles as Xb (bf16 X)
  short* Xb  = AO;  // X-cast consumed before attn writes AO
  short* Wto = Wcat + 3 * (size_t)D_MODEL * D_MODEL;

  xcast_k<<<dim3(M_TOT * D_MODEL / 2048), 256, 0, stream>>>(X, Xb);
  wtrans_k<<<dim3(32, 32, 4), dim3(32, 8), 0, stream>>>(Wq, Wk, Wv, Wo, Wcat);

  gemm_qkv_k<<<dim3(512), 256, 0, stream>>>(Xb, Wcat, bq, bk, bv,
                                            Qb, Kb, Vtb);

  attn_k<<<dim3(1024), 256, 0, stream>>>(Qb, Kb, Vtb, AO);

  gemm_o_k<<<dim3(512), 256, 0, stream>>>(AO, Wto, bo, (float*)d_out);
}

// Round 12
// 103.480 us; speedup vs baseline: 1.4598x; 1.0215x over previous
//
#include <hip/hip_runtime.h>
#include <hip/hip_bf16.h>

#define S_LEN 2048
#define D_MODEL 1024
#define NHEAD 16
#define HDIM 64
#define BATCH 2
#define M_TOT (BATCH * S_LEN)   // 4096
#define KVB 64

typedef __attribute__((ext_vector_type(4))) float f32x4;
typedef __attribute__((ext_vector_type(4))) short s16x4;
typedef __attribute__((ext_vector_type(8))) short s16x8;

#define AS1 __attribute__((address_space(1)))
#define AS3 __attribute__((address_space(3)))

#define SC2 0.18033688011112042f  // (1/8) * log2(e)

// Counted vmcnt wait (T4): lets next-tile loads stay in flight across the
// barrier. "memory" clobber keeps LDS reads from crossing.
#define WAITVM(N) asm volatile("s_waitcnt vmcnt(" #N ")" ::: "memory")

__device__ inline short f2bf(float f) {
  unsigned u = __float_as_uint(f);
  return (short)((u + 0x7fffu + ((u >> 16) & 1u)) >> 16);
}

// HW packed f32->bf16 (RNE). No builtin on gfx950 -> inline asm (T12 recipe).
__device__ __forceinline__ unsigned cvtpk(float lo, float hi) {
  unsigned r;
  asm("v_cvt_pk_bf16_f32 %0, %1, %2" : "=v"(r) : "v"(lo), "v"(hi));
  return r;
}
__device__ __forceinline__ s16x4 pk4(float a, float b, float c, float d) {
  union { unsigned u[2]; s16x4 s; } x;
  x.u[0] = cvtpk(a, b);
  x.u[1] = cvtpk(c, d);
  return x.s;
}

__device__ __forceinline__ void gl_lds16(const short* g, short* l) {
  __builtin_amdgcn_global_load_lds((const AS1 void*)g, (AS3 void*)l, 16, 0, 0);
}

// ---------------------------------------------------------------------------
// X fp32 -> bf16 cast. grid 2048, block 256, 8 elems/thread.
// ---------------------------------------------------------------------------
__global__ __launch_bounds__(256) void xcast_k(const float* __restrict__ X,
                                               short* __restrict__ Xb) {
  const size_t i = ((size_t)blockIdx.x * 256 + threadIdx.x) * 8;
  float4 a = *(const float4*)&X[i];
  float4 b = *(const float4*)&X[i + 4];
  s16x8 p;
  p[0] = f2bf(a.x); p[1] = f2bf(a.y); p[2] = f2bf(a.z); p[3] = f2bf(a.w);
  p[4] = f2bf(b.x); p[5] = f2bf(b.y); p[6] = f2bf(b.z); p[7] = f2bf(b.w);
  *(s16x8*)&Xb[i] = p;
}

// ---------------------------------------------------------------------------
// Weight transpose + cast, all 4 weights into contiguous Wcat[z][n][k].
// Wq (z==0) pre-scaled by (1/8)*log2(e). grid (32,32,4), block (32,8)
// ---------------------------------------------------------------------------
__global__ __launch_bounds__(256) void wtrans_k(const float* __restrict__ W0,
                                                const float* __restrict__ W1,
                                                const float* __restrict__ W2,
                                                const float* __restrict__ W3,
                                                short* __restrict__ Wcat) {
  const int z = blockIdx.z;
  const float* W = z == 0 ? W0 : z == 1 ? W1 : z == 2 ? W2 : W3;
  short* Wt = Wcat + (size_t)z * D_MODEL * D_MODEL;
  const float scl = (z == 0) ? SC2 : 1.f;
  __shared__ float tile[32][33];
  const int tx = threadIdx.x, ty = threadIdx.y;
  const int n0 = blockIdx.x * 32, k0 = blockIdx.y * 32;
#pragma unroll
  for (int j = 0; j < 4; ++j)
    tile[ty + j * 8][tx] = W[(size_t)(k0 + ty + j * 8) * D_MODEL + n0 + tx];
  __syncthreads();
#pragma unroll
  for (int j = 0; j < 4; ++j)
    Wt[(size_t)(n0 + ty + j * 8) * D_MODEL + k0 + tx] =
        f2bf(tile[tx][ty + j * 8] * scl);
}

// ---------------------------------------------------------------------------
// Fused QKV projection: tile 128x192, BK=64, grid 512, 80KB LDS, 2 blocks/CU.
// Round 12: counted-vmcnt pipeline (T4). Per K-step per wave the stage is
// 10 global_load_lds. Schedule:
//   prologue: stage(t0); stage(t1)                     [20 in flight]
//   iter t:   WAITVM(10)  -> tile t landed, tile t+1 STAYS IN FLIGHT
//             s_barrier   -> all waves' portions visible
//             ds_read + MFMA (tile t)
//             s_barrier   -> all waves done reading buf before overwrite
//             stage(buf, t+2)
// (replaces __syncthreads whose vmcnt(0) drained the prefetch every step)
// ---------------------------------------------------------------------------
__global__ __launch_bounds__(256, 2) void gemm_qkv_k(
    const short* __restrict__ Xb, const short* __restrict__ Wcat,
    const float* __restrict__ bq, const float* __restrict__ bk,
    const float* __restrict__ bv, short* __restrict__ Qb,
    short* __restrict__ Kb, short* __restrict__ Vtb) {
  __shared__ short As[2 * 128 * 64];   // 32 KB
  __shared__ short Bs[2 * 192 * 64];   // 48 KB
  const int orig = blockIdx.x;                 // 512
  const int xcd = orig & 7;                    // chunk = XCD
  const int k = orig >> 3;                     // 0..63 within chunk
  const int m0 = (((xcd & 3) << 3) + (k & 7)) * 128;
  const int n0 = (((xcd >> 2) << 3) + (k >> 3)) * 192;

  const int tid = threadIdx.x;
  const int lane = tid & 63, w = tid >> 6;
  const int wm = w >> 1, wn = w & 1;
  const int lr = lane & 15, lg = lane >> 4;
  const int lr8 = lane >> 3;
  const int sl = lane & 7;
  const int scol = ((sl ^ lr8) << 3);

  f32x4 acc[4][6] = {};

  auto stage = [&](int buf, int k0) {
#pragma unroll
    for (int j = 0; j < 4; ++j) {
      const int rb = j * 4 + w;
      const int row = rb * 8 + lr8;
      gl_lds16(&Xb[(size_t)(m0 + row) * D_MODEL + k0 + scol],
               &As[buf * 8192 + rb * 512]);
    }
#pragma unroll
    for (int j = 0; j < 6; ++j) {
      const int rb = j * 4 + w;
      const int row = rb * 8 + lr8;
      gl_lds16(&Wcat[(size_t)(n0 + row) * D_MODEL + k0 + scol],
               &Bs[buf * 12288 + rb * 512]);
    }
  };

  stage(0, 0);
  stage(1, 64);

  for (int t = 0; t < D_MODEL / 64; ++t) {
    const int cur = t & 1;
    if (t + 1 < D_MODEL / 64) { WAITVM(10); } else { WAITVM(0); }
    __builtin_amdgcn_s_barrier();
    __builtin_amdgcn_sched_barrier(0);
    const short* Ac = As + cur * 8192;
    const short* Bc = Bs + cur * 12288;
#pragma unroll
    for (int ks = 0; ks < 2; ++ks) {
      s16x8 af[4], bfr[6];
#pragma unroll
      for (int i = 0; i < 4; ++i) {
        const int Ra = wm * 64 + i * 16 + lr;
        af[i] = *(const s16x8*)&Ac[Ra * 64 + ((((ks << 2) | lg) ^ (Ra & 7)) << 3)];
      }
#pragma unroll
      for (int i = 0; i < 6; ++i) {
        const int Rb = wn * 96 + i * 16 + lr;
        bfr[i] = *(const s16x8*)&Bc[Rb * 64 + ((((ks << 2) | lg) ^ (Rb & 7)) << 3)];
      }
      __builtin_amdgcn_s_setprio(1);
#pragma unroll
      for (int mi = 0; mi < 4; ++mi)
#pragma unroll
        for (int ni = 0; ni < 6; ++ni)
          acc[mi][ni] = __builtin_amdgcn_mfma_f32_16x16x32_bf16(
              af[mi], bfr[ni], acc[mi][ni], 0, 0, 0);
      __builtin_amdgcn_s_setprio(0);
    }
    __builtin_amdgcn_sched_barrier(0);
    __builtin_amdgcn_s_barrier();
    if (t + 2 < D_MODEL / 64) stage(cur, (t + 2) * 64);
  }

#pragma unroll
  for (int ni = 0; ni < 6; ++ni) {
    const int n = n0 + wn * 96 + ni * 16 + lr;
    const int z = n >> 10;              // uniform within a 16-chunk
    const float bn = (z == 0 ? bq[n & 1023] * SC2
                             : (z == 1 ? bk[n & 1023] : bv[n & 1023]));
    short* Cp = z == 0 ? Qb : z == 1 ? Kb : Vtb;
    const int h = (n >> 6) & 15, d = n & 63;
#pragma unroll
    for (int mi = 0; mi < 4; ++mi) {
      const int mb = m0 + wm * 64 + mi * 16 + lg * 4;
      f32x4 v = acc[mi][ni];
      if (z < 2) {
#pragma unroll
        for (int j = 0; j < 4; ++j) {
          int m = mb + j;
          int b = m >> 11, s = m & 2047;
          Cp[((size_t)((b * NHEAD + h) * S_LEN) + s) * HDIM + d] = f2bf(v[j] + bn);
        }
      } else {
        int b = mb >> 11, s = mb & 2047;
        s16x4 p;
#pragma unroll
        for (int j = 0; j < 4; ++j) p[j] = f2bf(v[j] + bn);
        *(s16x4*)&Cp[((size_t)((b * NHEAD + h) * HDIM) + d) * S_LEN + s] = p;
      }
    }
  }
}

// ---------------------------------------------------------------------------
// Output projection: tile 128x64, BK=64, grid 512, XCD-chunked 8x8 mapping.
// Counted-vmcnt pipeline: stage = 6 loads/wave -> WAITVM(6).
// ---------------------------------------------------------------------------
__global__ __launch_bounds__(256, 2) void gemm_o_k(const short* __restrict__ A,
                                                   const short* __restrict__ Bt,
                                                   const float* __restrict__ bias,
                                                   float* __restrict__ C) {
  __shared__ short As[2 * 128 * 64];   // 32 KB
  __shared__ short Bs[2 * 64 * 64];    // 16 KB
  const int orig = blockIdx.x;                 // 512
  const int xcd = orig & 7;
  const int k = orig >> 3;
  const int m0 = (((xcd & 3) << 3) + (k & 7)) * 128;
  const int n0 = (((xcd >> 2) << 3) + (k >> 3)) * 64;

  const int tid = threadIdx.x;
  const int lane = tid & 63, w = tid >> 6;
  const int wm = w >> 1, wn = w & 1;
  const int lr = lane & 15, lg = lane >> 4;
  const int lr8 = lane >> 3;
  const int sl = lane & 7;
  const int scol = ((sl ^ lr8) << 3);

  f32x4 acc[4][2] = {};

  auto stage = [&](int buf, int k0) {
#pragma unroll
    for (int j = 0; j < 4; ++j) {
      const int rb = j * 4 + w;
      const int row = rb * 8 + lr8;
      gl_lds16(&A[(size_t)(m0 + row) * D_MODEL + k0 + scol],
               &As[buf * 8192 + rb * 512]);
    }
#pragma unroll
    for (int j = 0; j < 2; ++j) {
      const int rb = j * 4 + w;
      const int row = rb * 8 + lr8;
      gl_lds16(&Bt[(size_t)(n0 + row) * D_MODEL + k0 + scol],
               &Bs[buf * 4096 + rb * 512]);
    }
  };

  stage(0, 0);
  stage(1, 64);

  for (int t = 0; t < D_MODEL / 64; ++t) {
    const int cur = t & 1;
    if (t + 1 < D_MODEL / 64) { WAITVM(6); } else { WAITVM(0); }
    __builtin_amdgcn_s_barrier();
    __builtin_amdgcn_sched_barrier(0);
    const short* Ac = As + cur * 8192;
    const short* Bc = Bs + cur * 4096;
#pragma unroll
    for (int ks = 0; ks < 2; ++ks) {
      s16x8 af[4], bfr[2];
#pragma unroll
      for (int i = 0; i < 4; ++i) {
        const int Ra = wm * 64 + i * 16 + lr;
        af[i] = *(const s16x8*)&Ac[Ra * 64 + ((((ks << 2) | lg) ^ (Ra & 7)) << 3)];
      }
#pragma unroll
      for (int i = 0; i < 2; ++i) {
        const int Rb = wn * 32 + i * 16 + lr;
        bfr[i] = *(const s16x8*)&Bc[Rb * 64 + ((((ks << 2) | lg) ^ (Rb & 7)) << 3)];
      }
      __builtin_amdgcn_s_setprio(1);
#pragma unroll
      for (int mi = 0; mi < 4; ++mi)
#pragma unroll
        for (int ni = 0; ni < 2; ++ni)
          acc[mi][ni] = __builtin_amdgcn_mfma_f32_16x16x32_bf16(
              af[mi], bfr[ni], acc[mi][ni], 0, 0, 0);
      __builtin_amdgcn_s_setprio(0);
    }
    __builtin_amdgcn_sched_barrier(0);
    __builtin_amdgcn_s_barrier();
    if (t + 2 < D_MODEL / 64) stage(cur, (t + 2) * 64);
  }

#pragma unroll
  for (int ni = 0; ni < 2; ++ni) {
    const int n = n0 + wn * 32 + ni * 16 + lr;
    const float bn = bias[n];
#pragma unroll
    for (int mi = 0; mi < 2 * 2; ++mi) {
      const int mb = m0 + wm * 64 + mi * 16 + lg * 4;
      f32x4 v = acc[mi][ni];
#pragma unroll
      for (int j = 0; j < 4; ++j)
        C[(size_t)(mb + j) * D_MODEL + n] = v[j] + bn;
    }
  }
}

// ---------------------------------------------------------------------------
// Flash attention (causal) — round-8/11 structure + counted-vmcnt pipeline.
// grid 1024, 64-row q-tile per block, 4 waves, 4 blocks/CU; bh-parity map
// (per-CU work = 66 units by construction under round-robin dispatch).
// Stage = 4 global_load_lds per wave -> WAITVM(4) steady state.
// ---------------------------------------------------------------------------
__global__ __launch_bounds__(256, 4) void attn_k(const short* __restrict__ Q,
                                                 const short* __restrict__ K,
                                                 const short* __restrict__ Vt,
                                                 short* __restrict__ AO) {
  __shared__ short Ks[2][KVB * HDIM];
  __shared__ short Vs[2][HDIM * KVB];
  const int tid = threadIdx.x, w = tid >> 6, lane = tid & 63;
  const int lr = lane & 15, lg = lane >> 4;
  const int orig = blockIdx.x;
  const int wg = (orig & 7) * 128 + (orig >> 3);
  const int bh = wg >> 5, qi = wg & 31;
  const int qt = (bh & 1) ? qi : 31 - qi;   // balanced map (round-8)
  const int q0 = qt * 64, nt = qt + 1;
  const int b = bh >> 4, h = bh & 15;
  const size_t headQK = (size_t)bh * S_LEN * HDIM;
  const size_t headV = (size_t)bh * HDIM * S_LEN;
  const int qrow = q0 + w * 16 + lr;

  const int l8 = lane >> 3, sl = lane & 7;
  const int scol = ((sl ^ l8) << 3);

  auto stage = [&](int kv0, int buf) {
#pragma unroll
    for (int j = 0; j < 2; ++j) {
      const int rb = w * 2 + j;
      const int row = rb * 8 + l8;
      gl_lds16(&K[headQK + (size_t)(kv0 + row) * HDIM + scol],
               &Ks[buf][rb * 512]);
      gl_lds16(&Vt[headV + (size_t)row * S_LEN + kv0 + scol],
               &Vs[buf][rb * 512]);
    }
  };

  const s16x8 qf0 = *(const s16x8*)&Q[headQK + (size_t)qrow * HDIM + lg * 8];
  const s16x8 qf1 = *(const s16x8*)&Q[headQK + (size_t)qrow * HDIM + 32 + lg * 8];

  f32x4 o[4] = {};
  float m_run = -1e30f;
  float l_part = 0.f;

  stage(0, 0);
  if (nt > 1) stage(KVB, 1);

  for (int t = 0; t < nt; ++t) {
    if (t + 1 < nt) { WAITVM(4); } else { WAITVM(0); }
    __builtin_amdgcn_s_barrier();
    __builtin_amdgcn_sched_barrier(0);
    const short* Kc = Ks[t & 1];
    const short* Vc = Vs[t & 1];
    const bool diag = (t == nt - 1);
    const int gmax = diag ? (w + 1) : 4;   // wave-uniform

    // scores^T (already scaled to log2 domain): S^T = K @ Q'^T
    f32x4 sc[4];
    __builtin_amdgcn_s_setprio(1);
#pragma unroll
    for (int g = 0; g < 4; ++g) {
      if (g < gmax) {
        const int R = g * 16 + lr;
        const s16x8 kf0 = *(const s16x8*)&Kc[R * 64 + ((lg ^ (lr & 7)) << 3)];
        const s16x8 kf1 = *(const s16x8*)&Kc[R * 64 + (((4 | lg) ^ (lr & 7)) << 3)];
        f32x4 z = {0.f, 0.f, 0.f, 0.f};
        sc[g] = __builtin_amdgcn_mfma_f32_16x16x32_bf16(kf0, qf0, z, 0, 0, 0);
        sc[g] = __builtin_amdgcn_mfma_f32_16x16x32_bf16(kf1, qf1, sc[g], 0, 0, 0);
      }
    }
    __builtin_amdgcn_s_setprio(0);

    if (diag) {  // element mask only needed for the partial group g == w
#pragma unroll
      for (int g = 0; g < 4; ++g)
        if (g == w) {
#pragma unroll
          for (int j = 0; j < 4; ++j)
            if (lg * 4 + j > lr) sc[g][j] = -1e30f;
        }
    }

    // per-lane max over active groups
    float tm = -1e30f;
#pragma unroll
    for (int g = 0; g < 4; ++g)
      if (g < gmax)
        tm = fmaxf(tm, fmaxf(fmaxf(sc[g][0], sc[g][1]),
                             fmaxf(sc[g][2], sc[g][3])));

    // defer-max: full row-max reduce + rescale only when some row grew >THR=8
    if (!__all(tm <= m_run + 8.f)) {
      float tr = fmaxf(tm, m_run);
      tr = fmaxf(tr, __shfl_xor(tr, 16));
      tr = fmaxf(tr, __shfl_xor(tr, 32));
      const float corr = __builtin_amdgcn_exp2f(m_run - tr);
      l_part *= corr;
#pragma unroll
      for (int dc = 0; dc < 4; ++dc) o[dc] = o[dc] * corr;
      m_run = tr;
    }

    // P = exp2(sc - m_run), pack via HW cvt_pk, accumulate per-lane l
    s16x4 pf[4];
#pragma unroll
    for (int g = 0; g < 4; ++g) {
      if (g < gmax) {
        const float e0 = __builtin_amdgcn_exp2f(sc[g][0] - m_run);
        const float e1 = __builtin_amdgcn_exp2f(sc[g][1] - m_run);
        const float e2 = __builtin_amdgcn_exp2f(sc[g][2] - m_run);
        const float e3 = __builtin_amdgcn_exp2f(sc[g][3] - m_run);
        pf[g] = pk4(e0, e1, e2, e3);
        l_part += (e0 + e1) + (e2 + e3);
      }
    }

    __builtin_amdgcn_s_setprio(1);
#pragma unroll
    for (int g = 0; g < 4; ++g) {
      if (g < gmax) {
#pragma unroll
        for (int dc = 0; dc < 4; ++dc) {
          const int row = dc * 16 + lr;
          const s16x4 vf = *(const s16x4*)&Vc[row * 64 +
              (((2 * g + (lg >> 1)) ^ (lr & 7)) << 3) + ((lg & 1) << 2)];
          o[dc] = __builtin_amdgcn_mfma_f32_16x16x16bf16_1k(vf, pf[g], o[dc], 0, 0, 0);
        }
      }
    }
    __builtin_amdgcn_s_setprio(0);
    __builtin_amdgcn_sched_barrier(0);
    __builtin_amdgcn_s_barrier();
    if (t + 2 < nt) stage((t + 2) * KVB, t & 1);
  }

  // single end-of-tile cross-lane reduce of the partial l
  float lt = l_part;
  lt += __shfl_xor(lt, 16);
  lt += __shfl_xor(lt, 32);
  const float inv = 1.f / lt;
#pragma unroll
  for (int dc = 0; dc < 4; ++dc) {
    s16x4 pk;
#pragma unroll
    for (int j = 0; j < 4; ++j) pk[j] = f2bf(o[dc][j] * inv);
    *(s16x4*)&AO[((size_t)(b * S_LEN + qrow)) * D_MODEL + h * HDIM + dc * 16 + lg * 4] = pk;
  }
}

// ---------------------------------------------------------------------------
extern "C" void kernel_launch(void* const* d_in, const int* in_sizes, int n_in,
                              void* d_out, int out_size, void* d_ws, size_t ws_size,
                              hipStream_t stream) {
  const float* X  = (const float*)d_in[0];
  const float* Wq = (const float*)d_in[1];
  const float* bq = (const float*)d_in[2];
  const float* Wk = (const float*)d_in[3];
  const float* bk = (const float*)d_in[4];
  const float* Wv = (const float*)d_in[5];
  const float* bv = (const float*)d_in[6];
  const float* Wo = (const float*)d_in[7];
  const float* bo = (const float*)d_in[8];
  (void)in_sizes; (void)n_in; (void)out_size; (void)ws_size;

  char* ws = (char*)d_ws;
  const size_t WSZ = (size_t)D_MODEL * D_MODEL * sizeof(short);  // 2 MB
  const size_t QSZ = (size_t)M_TOT * D_MODEL * sizeof(short);    // 8 MB
  short* Wcat = (short*)ws;                       // 4 matrices, 8 MB
  short* Qb  = (short*)(ws + 4 * WSZ);
  short* Kb  = (short*)(ws + 4 * WSZ + QSZ);
  short* Vtb = (short*)(ws + 4 * WSZ + 2 * QSZ);
  short* AO  = (short*)(ws + 4 * WSZ + 3 * QSZ);  // doubles as Xb (bf16 X)
  short* Xb  = AO;  // X-cast consumed before attn writes AO
  short* Wto = Wcat + 3 * (size_t)D_MODEL * D_MODEL;

  xcast_k<<<dim3(M_TOT * D_MODEL / 2048), 256, 0, stream>>>(X, Xb);
  wtrans_k<<<dim3(32, 32, 4), dim3(32, 8), 0, stream>>>(Wq, Wk, Wv, Wo, Wcat);

  gemm_qkv_k<<<dim3(512), 256, 0, stream>>>(Xb, Wcat, bq, bk, bv,
                                            Qb, Kb, Vtb);

  attn_k<<<dim3(1024), 256, 0, stream>>>(Qb, Kb, Vtb, AO);

  gemm_o_k<<<dim3(512), 256, 0, stream>>>(AO, Wto, bo, (float*)d_out);
}